// Round 11
// baseline (81.141 us; speedup 1.0000x reference)
//
#include <hip/hip_runtime.h>

#define M_ROWS 1024
#define DIM 512
#define NB 1024              // row bytes = DIM*2
#define N_TOT 7168           // M + 2*M*C
#define TEXT_OFF 1024
#define SHUF_OFF 4096
#define INV_T (1.0f/0.07f)
#define MARGIN_V 0.2f
#define TILES 56             // N_TOT / 128
#define NBLK 1596            // 56*57/2 upper-triangular 128^2 tiles
#define SLOT 768             // floats per slot: [2 sides][3 vals][128 rows]

typedef __attribute__((ext_vector_type(8))) short bf16x8;
typedef __attribute__((ext_vector_type(4))) float f32x4;

typedef const __attribute__((address_space(1))) unsigned int gas_uint;
typedef __attribute__((address_space(3))) unsigned int las_uint;

__device__ __forceinline__ void gload16(const void* g, void* l) {
  __builtin_amdgcn_global_load_lds((gas_uint*)g, (las_uint*)l, 16, 0, 0);
}

__device__ __forceinline__ ushort f2bf(float f) {
  unsigned u = __float_as_uint(f);
  u += 0x7fffu + ((u >> 16) & 1u);   // RTNE
  return (ushort)(u >> 16);
}

// DPP 16-lane row sum on the VALU pipe; total lands in lane 15 of each row.
__device__ __forceinline__ float dpp_sum16(float x) {
  float s = x;
  s += __int_as_float(__builtin_amdgcn_update_dpp(0, __float_as_int(s), 0x111, 0xF, 0xF, true));
  s += __int_as_float(__builtin_amdgcn_update_dpp(0, __float_as_int(s), 0x112, 0xF, 0xF, true));
  s += __int_as_float(__builtin_amdgcn_update_dpp(0, __float_as_int(s), 0x114, 0xF, 0xF, true));
  s += __int_as_float(__builtin_amdgcn_update_dpp(0, __float_as_int(s), 0x118, 0xF, 0xF, true));
  return s;
}

// ------- Kernel 1: normalize + cast bf16 + build ids + zero ticket -------
__global__ __launch_bounds__(256) void k_normalize(
    const float* __restrict__ motion, const float* __restrict__ text,
    const float* __restrict__ shuf, const int* __restrict__ mids,
    ushort* __restrict__ emb, int* __restrict__ ids, int* __restrict__ ticket) {
  if (blockIdx.x == 0 && threadIdx.x == 0) *ticket = 0;
  int wave = threadIdx.x >> 6;
  int lane = threadIdx.x & 63;
  int row = blockIdx.x * 4 + wave;
  if (row >= N_TOT) return;
  const float* src;
  int id;
  if (row < TEXT_OFF) { src = motion + (size_t)row * DIM; id = mids[row]; }
  else if (row < SHUF_OFF) { int r = row - TEXT_OFF; src = text + (size_t)r * DIM; id = mids[r / 3]; }
  else { int r = row - SHUF_OFF; src = shuf + (size_t)r * DIM; id = mids[r / 3] + 100000; }

  float4 a = ((const float4*)src)[lane * 2];
  float4 b = ((const float4*)src)[lane * 2 + 1];
  float v0 = a.x + 1e-8f, v1 = a.y + 1e-8f, v2 = a.z + 1e-8f, v3 = a.w + 1e-8f;
  float v4 = b.x + 1e-8f, v5 = b.y + 1e-8f, v6 = b.z + 1e-8f, v7 = b.w + 1e-8f;
  float ss = v0*v0 + v1*v1 + v2*v2 + v3*v3 + v4*v4 + v5*v5 + v6*v6 + v7*v7;
  #pragma unroll
  for (int m = 1; m < 64; m <<= 1) ss += __shfl_xor(ss, m);
  float inv = 1.0f / fmaxf(sqrtf(ss), 1e-12f);

  uint w0 = (uint)f2bf(v0 * inv) | ((uint)f2bf(v1 * inv) << 16);
  uint w1 = (uint)f2bf(v2 * inv) | ((uint)f2bf(v3 * inv) << 16);
  uint w2 = (uint)f2bf(v4 * inv) | ((uint)f2bf(v5 * inv) << 16);
  uint w3 = (uint)f2bf(v6 * inv) | ((uint)f2bf(v7 * inv) << 16);
  uint4 pk; pk.x = w0; pk.y = w1; pk.z = w2; pk.w = w3;
  *((uint4*)(emb + (size_t)row * DIM + lane * 8)) = pk;
  if (lane == 0) ids[row] = id;
}

// -------- Kernel 2: symmetric fused A*A^T, 128^2 tiles, 4 waves --------
// Small work quantum for CO-RESIDENCY: acc 64 VGPR + LDS 48 KB ->
// 3 blocks/CU, 12 waves/CU; co-resident blocks hide each other's stalls.
// Triple-buffered counted-vmcnt pipeline; 2-way-free LDS swizzle; DPP
// epilogue; slot-based partials (no global atomics).
__global__ __launch_bounds__(256, 3) void k_gemm_loss(
    const ushort* __restrict__ emb, const int* __restrict__ ids,
    float* __restrict__ part) {
  __shared__ ushort Asm[3][4096];   // [buf][128 rows x 32 bf16] = 8 KB per buf
  __shared__ ushort Bsm[3][4096];   // total static LDS = 48 KB

  // bijective XCD-chunked swizzle: nwg=1596, q=199, r=4
  int orig = blockIdx.x;
  int xcd = orig & 7;
  int idx = orig >> 3;
  int bid = (xcd < 4 ? xcd * 200 : 800 + (xcd - 4) * 199) + idx;

  // triangular tile decode: bid -> (x, y), x <= y
  int x = 0;
  while (bid >= TILES - x) { bid -= TILES - x; x++; }
  int y = x + bid;
  bool diag = (x == y);
  int brow = x * 128, bcol = y * 128;
  int tbid = x * TILES - x * (x - 1) / 2 + (y - x);   // linear triangular id

  int t = threadIdx.x;
  int l = t & 63;
  int w = t >> 6;            // wave 0..3
  int wr = w >> 1;           // wave row 0..1  -> 64 output rows each
  int wc = w & 1;            // wave col 0..1  -> 64 output cols each
  int fr = l & 15;
  int fg = l >> 4;           // 0..3

  // staging: lane l stages row (w*16 + l>>2) of each 64-row chunk,
  // source col pre-swizzled so linear gload_lds dest holds swizzled layout
  int srow = w * 16 + (l >> 2);
  int scol = ((l & 3) ^ ((l >> 3) & 3)) * 16;
  const char* gA = (const char*)emb + (size_t)(brow + srow) * NB + scol;
  const char* gB = (const char*)emb + (size_t)(bcol + srow) * NB + scol;
  int ldso = w * 512;

  f32x4 acc[4][4];
  #pragma unroll
  for (int m = 0; m < 4; m++)
    #pragma unroll
    for (int n = 0; n < 4; n++)
      acc[m][n] = (f32x4){0.f, 0.f, 0.f, 0.f};

  // swizzled ds_read col offset (ushorts): phys colgroup = fg ^ ((row>>1)&3)
  int swz = (fg ^ ((fr >> 1) & 3)) * 8;

#define STAGE(T) do { \
    const int _b = (T) % 3; const int _kb = (T) * 64; \
    gload16(gA + _kb,         &Asm[_b][ldso]); \
    gload16(gA + 65536 + _kb, &Asm[_b][2048 + ldso]); \
    gload16(gB + _kb,         &Bsm[_b][ldso]); \
    gload16(gB + 65536 + _kb, &Bsm[_b][2048 + ldso]); \
  } while (0)

  // prologue: tiles 0 and 1 in flight; wait tile 0 only
  STAGE(0);
  STAGE(1);
  asm volatile("s_waitcnt vmcnt(4)" ::: "memory");
  __builtin_amdgcn_s_barrier();

  #pragma unroll
  for (int tt = 0; tt < 16; tt++) {
    if (tt + 2 < 16) STAGE(tt + 2);   // disjoint buffer: no read conflict
    const int _b = tt % 3;
    const ushort* Ab = &Asm[_b][(wr * 64 + fr) * 32 + swz];
    const ushort* Bb = &Bsm[_b][(wc * 64 + fr) * 32 + swz];
    bf16x8 aF[4], bF[4];
    #pragma unroll
    for (int m = 0; m < 4; m++) aF[m] = *(const bf16x8*)(Ab + m * 512);
    #pragma unroll
    for (int n = 0; n < 4; n++) bF[n] = *(const bf16x8*)(Bb + n * 512);
    __builtin_amdgcn_s_setprio(1);
    #pragma unroll
    for (int m = 0; m < 4; m++)
      #pragma unroll
      for (int n = 0; n < 4; n++)
        acc[m][n] = __builtin_amdgcn_mfma_f32_16x16x32_bf16(aF[m], bF[n], acc[m][n], 0, 0, 0);
    __builtin_amdgcn_s_setprio(0);
    if (tt < 14) {
      asm volatile("s_waitcnt vmcnt(4)" ::: "memory");   // retire tile tt+1
      __builtin_amdgcn_s_barrier();
    } else if (tt == 14) {
      asm volatile("s_waitcnt vmcnt(0)" ::: "memory");
      __builtin_amdgcn_s_barrier();
    }
  }
#undef STAGE

  // ---- reuse LDS after K-loop (full drain barrier first) ----
  __syncthreads();
  float* rpd = (float*)&Asm[1][0];      // [4 waves][64 rows]
  float* rpp = rpd + 256;
  float* rpm = rpp + 256;
  float* cps = (float*)&Bsm[1][0];      // [4 waves][4 n][16 cl][3]
  int* ridL = (int*)&Asm[2][0];
  int* cidL = ridL + 128;
  if (t < 128) ridL[t] = ids[brow + t];
  else cidL[t - 128] = ids[bcol + (t - 128)];
  __syncthreads();

  float* ps = part + (size_t)tbid * SLOT;   // [side][3 vals][128]

  // ---- epilogue: per-element masks; DPP row-reduce ----
  int cl = fr;
  int cgrp = fg;
  int cidv[4];
  #pragma unroll
  for (int n = 0; n < 4; n++) cidv[n] = cidL[wc * 64 + n * 16 + cl];
  float cd[4], cp[4], cm[4];
  #pragma unroll
  for (int n = 0; n < 4; n++) { cd[n] = 0.f; cp[n] = 0.f; cm[n] = 0.f; }

  #pragma unroll
  for (int m = 0; m < 4; m++) {
    #pragma unroll
    for (int r = 0; r < 4; r++) {
      int row_l = wr * 64 + m * 16 + cgrp * 4 + r;
      int i = brow + row_l;
      int idi = ridL[row_l];
      float dsum = 0.f, psum = 0.f, msum = 0.f;
      #pragma unroll
      for (int n = 0; n < 4; n++) {
        int col_l = wc * 64 + n * 16 + cl;
        int j = bcol + col_l;
        float sim = acc[m][n][r] * INV_T;
        bool live = (!diag) || (i != j);
        if (live) {
          float e = __expf(sim);
          float hinge = fmaxf(sim + MARGIN_V, 0.f);
          bool same = (idi == cidv[n]);
          float psv = same ? sim : 0.f;
          float msv = same ? 0.f : hinge;
          dsum += e; psum += psv; msum += msv;
          if (!diag) { cd[n] += e; cp[n] += psv; cm[n] += msv; }
        }
      }
      dsum = dpp_sum16(dsum);
      psum = dpp_sum16(psum);
      msum = dpp_sum16(msum);
      if (cl == 15) {
        int o = w * 64 + (row_l & 63);
        rpd[o] = dsum; rpp[o] = psum; rpm[o] = msum;
      }
    }
  }

  if (!diag) {
    // col partials: shfl-combine the 4 fg-groups within the wave
    #pragma unroll
    for (int n = 0; n < 4; n++) {
      float d = cd[n], p = cp[n], mm = cm[n];
      d += __shfl_xor(d, 16); d += __shfl_xor(d, 32);
      p += __shfl_xor(p, 16); p += __shfl_xor(p, 32);
      mm += __shfl_xor(mm, 16); mm += __shfl_xor(mm, 32);
      if (l < 16) {
        int o = ((w * 4 + n) * 16 + cl) * 3;
        cps[o] = d; cps[o + 1] = p; cps[o + 2] = mm;
      }
    }
  }
  __syncthreads();

  // row side: sum the 2 wc-wave slices, coalesced store
  if (t < 128) {
    int b0 = (t >> 6) * 128 + (t & 63);
    float d = rpd[b0] + rpd[b0 + 64];
    float p = rpp[b0] + rpp[b0 + 64];
    float mm = rpm[b0] + rpm[b0 + 64];
    ps[t] = d; ps[128 + t] = p; ps[256 + t] = mm;
  }
  // col side: combine wr=0/wr=1 pairs (w and w+2), store
  if (!diag && wr == 0 && l < 16) {
    #pragma unroll
    for (int n = 0; n < 4; n++) {
      int o0 = ((w * 4 + n) * 16 + cl) * 3;
      int o1 = (((w + 2) * 4 + n) * 16 + cl) * 3;
      int col_l = w * 64 + n * 16 + cl;   // wc == w when wr == 0
      ps[384 + col_l] = cps[o0] + cps[o1];
      ps[384 + 128 + col_l] = cps[o0 + 1] + cps[o1 + 1];
      ps[384 + 256 + col_l] = cps[o0 + 2] + cps[o1 + 2];
    }
  }
}

// ---- Kernel 3: reduce partials + per-row loss + ticket-gated final ----
__global__ __launch_bounds__(128) void k_reduce(
    const float* __restrict__ part, const int* __restrict__ mids,
    float* __restrict__ blockout, int* __restrict__ ticket,
    float* __restrict__ out) {
  __shared__ int hist[256];
  __shared__ float reds[128];
  __shared__ int redc[128];
  __shared__ int lastf;
  int t = threadIdx.x;
  hist[t] = 0; hist[t + 128] = 0;
  __syncthreads();
  for (int i = t; i < M_ROWS; i += 128) atomicAdd(&hist[mids[i]], 1);
  __syncthreads();

  int p = blockIdx.x;                      // panel 0..55
  int i = p * 128 + t;                     // row 0..7167
  float d = 0.f, pp = 0.f, mm = 0.f;
  int base = p * TILES - p * (p - 1) / 2;  // tbid(p, p)
  for (int yy = p; yy < TILES; yy++) {     // row-side from tiles (p, yy)
    const float* s = part + (size_t)(base + yy - p) * SLOT;
    d += s[t]; pp += s[128 + t]; mm += s[256 + t];
  }
  for (int xx = 0; xx < p; xx++) {         // col-side from tiles (xx, p)
    int b = xx * TILES - xx * (xx - 1) / 2 + (p - xx);
    const float* s = part + (size_t)b * SLOT + 384;
    d += s[t]; pp += s[128 + t]; mm += s[256 + t];
  }

  int vmid; bool sh = false;
  if (i < TEXT_OFF) vmid = mids[i];
  else if (i < SHUF_OFF) vmid = mids[(i - TEXT_OFF) / 3];
  else { vmid = mids[(i - SHUF_OFF) / 3]; sh = true; }
  int c = hist[vmid];
  int npos = sh ? (3 * c - 1) : (4 * c - 1);
  int nneg = N_TOT - 1 - npos;
  float val = 0.f; int cnt = 0;
  if (npos > 0 && nneg > 0) {
    val = logf(d) - pp / (float)(npos > 1 ? npos : 1) + mm / (float)(nneg > 1 ? nneg : 1);
    cnt = 1;
  }
  reds[t] = val; redc[t] = cnt;
  __syncthreads();
  for (int s2 = 64; s2 > 0; s2 >>= 1) {
    if (t < s2) { reds[t] += reds[t + s2]; redc[t] += redc[t + s2]; }
    __syncthreads();
  }
  if (t == 0) {
    blockout[p * 2] = reds[0];
    blockout[p * 2 + 1] = (float)redc[0];
    __threadfence();
    int old = atomicAdd(ticket, 1);
    lastf = (old == TILES - 1);
  }
  __syncthreads();
  if (lastf) {
    __threadfence();
    float s = (t < TILES) ? blockout[t * 2] : 0.f;
    float cc = (t < TILES) ? blockout[t * 2 + 1] : 0.f;
    reds[t] = s; redc[t] = (int)cc;
    __syncthreads();
    for (int s2 = 64; s2 > 0; s2 >>= 1) {
      if (t < s2) { reds[t] += reds[t + s2]; redc[t] += redc[t + s2]; }
      __syncthreads();
    }
    if (t == 0) out[0] = (redc[0] > 0) ? reds[0] / (float)redc[0] : 0.f;
  }
}

// ---------------- Launch ----------------
extern "C" void kernel_launch(void* const* d_in, const int* in_sizes, int n_in,
                              void* d_out, int out_size, void* d_ws, size_t ws_size,
                              hipStream_t stream) {
  const float* motion = (const float*)d_in[0];
  const float* text   = (const float*)d_in[1];
  const float* shuf   = (const float*)d_in[2];
  const int*   mids   = (const int*)d_in[3];

  char* ws = (char*)d_ws;
  ushort* emb = (ushort*)ws;                                  // 7,340,032 B
  int* ids    = (int*)(ws + 7340032);                         // 28,672 B
  float* blockout = (float*)(ws + 7368704);                   // 56*2 floats
  int* ticket = (int*)(ws + 7369216);                         // 4 B
  float* part = (float*)(ws + 7372800);                       // 1596*768*4 = 4,902,912 B

  k_normalize<<<N_TOT / 4, 256, 0, stream>>>(motion, text, shuf, mids, emb, ids, ticket);
  k_gemm_loss<<<NBLK, 256, 0, stream>>>(emb, ids, part);
  k_reduce<<<TILES, 128, 0, stream>>>(part, mids, blockout, ticket, (float*)d_out);
}